// Round 5
// baseline (142.076 us; speedup 1.0000x reference)
//
#include <hip/hip_runtime.h>
#include <hip/hip_bf16.h>

// CorrelatorK3: B=8, N=256, D=64, F=64
// Stage 1 (global_load_lds staging, 3-set LDS, depth-2 counted-vmcnt pipeline):
//   A[p,kk]  = (rbf0[p]·Q0w+Q0b) * (rbfd[p]·Qw+Qb)   (bf16, f-permuted kk)
//   Bm[p,kk] = (rbf0[p]·R0w+R0b) * (rbfd[p]·Rw+Rb)   (bf16, f-permuted kk)
//   kk = kg*16 + ft*4 + r  <->  f = ft*16 + kg*4 + r (same perm both bufs)
// Stage 2: C[b,n,j] = 0.02 * sum_{i,kk} A[b,n,i,kk] * Bm[b,i,j,kk]

typedef __bf16 bf16x8 __attribute__((ext_vector_type(8)));
typedef float  f32x4  __attribute__((ext_vector_type(4)));
typedef int    i32x4  __attribute__((ext_vector_type(4)));
typedef unsigned short u16;
typedef u16    u16x8  __attribute__((ext_vector_type(8)));

static __device__ __forceinline__ __bf16 f2bf(float x) {
  union { __hip_bfloat16 h; __bf16 b; } u;
  u.h = __float2bfloat16(x);
  return u.b;
}
static __device__ __forceinline__ u16 f2bfu(float x) {
  union { __hip_bfloat16 h; u16 s; } u;
  u.h = __float2bfloat16(x);
  return u.s;
}
static __device__ __forceinline__ float bfu2f(u16 s) {
  union { unsigned int u; float f; } v;
  v.u = ((unsigned int)s) << 16;
  return v.f;
}
static __device__ __forceinline__ void gload16(const float* gsrc, float* ldst) {
  __builtin_amdgcn_global_load_lds(
      (const __attribute__((address_space(1))) void*)gsrc,
      (__attribute__((address_space(3))) void*)ldst, 16, 0, 0);
}

// ---------------------------------------------------------------- stage 1 ---
// Grid MUST be 2048 x 256thr (4 waves). Block-tile = 32 positions (16 KB).
// 3 LDS sets (48 KB), depth-2 prefetch via global_load_lds width=16.
// Global source is PRE-SWIZZLED (involution c^=(c>>4)&15 within 16-chunk
// windows -> coalescing preserved); LDS dest linear (gl_lds requirement);
// LDS reads use the same swizzle. Per-wave per-iter vmem ops: 4 gl_lds + 2
// stores -> counted vmcnt N[it] = {8,10,12,12,12,12,8,4} (never 0 in loop).
// Two barriers/iter: (1) after counted vmcnt -> tile ready; (2) after compute
// -> set may be overwritten by tile it+3 (same set mod 3) next iter.
__global__ __launch_bounds__(256, 3) void k_phase1(
    const float* __restrict__ rbf0, const float* __restrict__ rbfd,
    const float* __restrict__ Q0w, const float* __restrict__ Q0b,
    const float* __restrict__ Qw,  const float* __restrict__ Qb,
    const float* __restrict__ R0w, const float* __restrict__ R0b,
    const float* __restrict__ Rw,  const float* __restrict__ Rb,
    u16* __restrict__ Aout, u16* __restrict__ Bout)
{
  __shared__ __align__(16) float lds[3][2][2048];

  const int tid  = threadIdx.x;
  const int lane = tid & 63;
  const int wave = tid >> 6;
  const int fr   = lane & 15;
  const int kg   = lane >> 4;
  const int role = wave >> 1;   // 0: Q-path (A), 1: R-path (Bm)
  const int s    = wave & 1;    // 16-pos sub-tile

  const float* W0 = role ? R0w : Q0w;
  const float* W1 = role ? Rw  : Qw;
  const float* B0 = role ? R0b : Q0b;
  const float* B1 = role ? Rb  : Qb;
  u16* __restrict__ Out = role ? Bout : Aout;

  // Weight A-frags: lane holds W[ft*16+fr][kt*32+kg*8+j]
  bf16x8 wf0[2][4], wf1[2][4];
#pragma unroll
  for (int kt = 0; kt < 2; ++kt)
#pragma unroll
    for (int ft = 0; ft < 4; ++ft) {
      const float* p0 = W0 + (ft * 16 + fr) * 64 + kt * 32 + kg * 8;
      const float* p1 = W1 + (ft * 16 + fr) * 64 + kt * 32 + kg * 8;
      f32x4 a = *(const f32x4*)p0, b = *(const f32x4*)(p0 + 4);
      f32x4 c = *(const f32x4*)p1, d = *(const f32x4*)(p1 + 4);
      bf16x8 w0v, w1v;
#pragma unroll
      for (int j = 0; j < 4; ++j) {
        w0v[j] = f2bf(a[j]); w0v[j + 4] = f2bf(b[j]);
        w1v[j] = f2bf(c[j]); w1v[j + 4] = f2bf(d[j]);
      }
      wf0[kt][ft] = w0v; wf1[kt][ft] = w1v;
    }

  // Bias, permuted idx = ft*4+r (value b[ft*16+kg*4+r]), packed bf16
  u16x8 pb0[2], pb1[2];
#pragma unroll
  for (int ft = 0; ft < 4; ++ft)
#pragma unroll
    for (int r = 0; r < 4; ++r) {
      int idx = ft * 4 + r;
      pb0[idx >> 3][idx & 7] = f2bfu(B0[ft * 16 + kg * 4 + r]);
      pb1[idx >> 3][idx & 7] = f2bfu(B1[ft * 16 + kg * 4 + r]);
    }

  // Pre-swizzled global chunk indices (involution; float offsets = chunk*4).
  // Wave w stages segments {w, w+4} of each array; seg*64+lane = tid / tid+256.
  const int g0 = tid, g1 = 256 + tid;
  const int c0 = ((g0 >> 4) << 4) | ((g0 & 15) ^ ((g0 >> 4) & 15));
  const int c1 = ((g1 >> 4) << 4) | ((g1 & 15) ^ ((g1 >> 4) & 15));
  const int f0 = c0 * 4, f1 = c1 * 4;                 // float offsets
  const int d0 = wave * 256, d1 = (wave + 4) * 256;   // LDS float offsets (linear)

  const int bt0 = blockIdx.x;   // gridDim.x == 2048, 8 tiles/block

#define S1_ISSUE(IT, SET)                                              \
  {                                                                    \
    const float* b0_ = rbf0 + (size_t)(bt0 + (IT) * 2048) * 2048;      \
    const float* b1_ = rbfd + (size_t)(bt0 + (IT) * 2048) * 2048;      \
    gload16(b0_ + f0, &lds[SET][0][d0]);                               \
    gload16(b0_ + f1, &lds[SET][0][d1]);                               \
    gload16(b1_ + f0, &lds[SET][1][d0]);                               \
    gload16(b1_ + f1, &lds[SET][1][d1]);                               \
  }

#define S1_COMPUTE(IT, SET)                                            \
  {                                                                    \
    const int row = s * 16 + fr; /* row&15 == fr */                    \
    f32x4 ra[4], rb[4];                                                \
    _Pragma("unroll")                                                  \
    for (int kt = 0; kt < 2; ++kt)                                     \
      _Pragma("unroll")                                                \
      for (int h = 0; h < 2; ++h) {                                    \
        int c = kt * 8 + kg * 2 + h;                                   \
        int chunk = (row << 4) | (c ^ fr);                             \
        ra[kt * 2 + h] = *(const f32x4*)&lds[SET][0][chunk * 4];       \
        rb[kt * 2 + h] = *(const f32x4*)&lds[SET][1][chunk * 4];       \
      }                                                                \
    bf16x8 x0f[2], xdf[2];                                             \
    _Pragma("unroll")                                                  \
    for (int kt = 0; kt < 2; ++kt)                                     \
      _Pragma("unroll")                                                \
      for (int j = 0; j < 4; ++j) {                                    \
        x0f[kt][j]     = f2bf(ra[kt * 2][j]);                          \
        x0f[kt][j + 4] = f2bf(ra[kt * 2 + 1][j]);                      \
        xdf[kt][j]     = f2bf(rb[kt * 2][j]);                          \
        xdf[kt][j + 4] = f2bf(rb[kt * 2 + 1][j]);                      \
      }                                                                \
    f32x4 acc0[4], acc1[4];                                            \
    _Pragma("unroll")                                                  \
    for (int ft = 0; ft < 4; ++ft)                                     \
      _Pragma("unroll")                                                \
      for (int r = 0; r < 4; ++r) {                                    \
        int idx = ft * 4 + r;                                          \
        acc0[ft][r] = bfu2f(pb0[idx >> 3][idx & 7]);                   \
        acc1[ft][r] = bfu2f(pb1[idx >> 3][idx & 7]);                   \
      }                                                                \
    _Pragma("unroll")                                                  \
    for (int kt = 0; kt < 2; ++kt)                                     \
      _Pragma("unroll")                                                \
      for (int ft = 0; ft < 4; ++ft) {                                 \
        acc0[ft] = __builtin_amdgcn_mfma_f32_16x16x32_bf16(            \
            wf0[kt][ft], x0f[kt], acc0[ft], 0, 0, 0);                  \
        acc1[ft] = __builtin_amdgcn_mfma_f32_16x16x32_bf16(            \
            wf1[kt][ft], xdf[kt], acc1[ft], 0, 0, 0);                  \
      }                                                                \
    u16x8 o0, o1;                                                      \
    _Pragma("unroll")                                                  \
    for (int ft = 0; ft < 4; ++ft)                                     \
      _Pragma("unroll")                                                \
      for (int r = 0; r < 4; ++r) {                                    \
        int idx = ft * 4 + r;                                          \
        float v = acc0[ft][r] * acc1[ft][r];                           \
        if (idx < 8) o0[idx & 7] = f2bfu(v); else o1[idx & 7] = f2bfu(v); \
      }                                                                \
    u16* dst = Out + ((size_t)((bt0 + (IT) * 2048) * 32 + s * 16 + fr)) * 64 + kg * 16; \
    *(u16x8*)dst       = o0;                                           \
    *(u16x8*)(dst + 8) = o1;                                           \
  }

#define S1_ITER(IT, NWAIT, DO_ISSUE)                                   \
  {                                                                    \
    if (DO_ISSUE) S1_ISSUE((IT) + 2, ((IT) + 2) % 3);                  \
    asm volatile("s_waitcnt vmcnt(" #NWAIT ")" ::: "memory");          \
    __builtin_amdgcn_s_barrier();                                      \
    __builtin_amdgcn_sched_barrier(0);                                 \
    S1_COMPUTE(IT, (IT) % 3);                                          \
    asm volatile("s_waitcnt lgkmcnt(0)" ::: "memory");                 \
    __builtin_amdgcn_s_barrier();                                      \
    __builtin_amdgcn_sched_barrier(0);                                 \
  }

  // prologue: tiles 0,1 -> sets 0,1
  S1_ISSUE(0, 0);
  S1_ISSUE(1, 1);

  S1_ITER(0,  8, 1);
  S1_ITER(1, 10, 1);
  S1_ITER(2, 12, 1);
  S1_ITER(3, 12, 1);
  S1_ITER(4, 12, 1);
  S1_ITER(5, 12, 1);
  S1_ITER(6,  8, 0);
  S1_ITER(7,  4, 0);

#undef S1_ITER
#undef S1_COMPUTE
#undef S1_ISSUE
}

// ---------------------------------------------------------------- stage 2 ---
// Grid: 512 blocks = 8 b * 2 nt * 2 jt * 16 kc. Block = 4 waves (2x2), tile 128x128.
__global__ __launch_bounds__(256, 2) void k_phase2(
    const u16* __restrict__ A, const u16* __restrict__ Bm,
    float* __restrict__ C)
{
  __shared__ __align__(16) u16 Alds[128 * 64];
  __shared__ __align__(16) u16 Blds[128 * 64];

  const int tid  = threadIdx.x;
  const int lane = tid & 63;
  const int wave = tid >> 6;
  const int fr   = lane & 15;
  const int kg   = lane >> 4;

  const int bid = blockIdx.x;
  const int kc = bid & 15;
  const int jt = (bid >> 4) & 1;
  const int nt = (bid >> 5) & 1;
  const int b  = bid >> 6;          // [0,8)
  const int n0 = nt * 128, j0 = jt * 128;
  const int wr = wave >> 1, wc = wave & 1;

  const u16* Ab = A  + (size_t)b * 4194304;
  const u16* Bb = Bm + (size_t)b * 4194304;

  f32x4 acc[4][4];
#pragma unroll
  for (int mt = 0; mt < 4; ++mt)
#pragma unroll
    for (int nn = 0; nn < 4; ++nn) {
      acc[mt][nn][0] = 0.f; acc[mt][nn][1] = 0.f; acc[mt][nn][2] = 0.f; acc[mt][nn][3] = 0.f;
    }

  for (int ii = 0; ii < 16; ++ii) {
    const int i = kc * 16 + ii;

    i32x4 va[4], vb[4];
#pragma unroll
    for (int rep = 0; rep < 4; ++rep) {
      int c = tid + rep * 256;
      int row = c >> 3, ch = c & 7;
      va[rep] = *(const i32x4*)(Ab + (size_t)(n0 + row) * 16384 + (size_t)i * 64 + ch * 8);
      vb[rep] = *(const i32x4*)(Bb + (size_t)i * 16384 + (size_t)(j0 + row) * 64 + ch * 8);
    }
    __syncthreads();
#pragma unroll
    for (int rep = 0; rep < 4; ++rep) {
      int c = tid + rep * 256;
      int row = c >> 3, ch = c & 7;
      int sw = ch ^ (row & 7);
      *(i32x4*)&Alds[row * 64 + sw * 8] = va[rep];
      *(i32x4*)&Blds[row * 64 + sw * 8] = vb[rep];
    }
    __syncthreads();

#pragma unroll
    for (int ks = 0; ks < 2; ++ks) {
      bf16x8 af[4], bfv[4];
#pragma unroll
      for (int mt = 0; mt < 4; ++mt) {
        int row = wr * 64 + mt * 16 + fr;
        int sw = (ks * 4 + kg) ^ (row & 7);
        af[mt] = *(const bf16x8*)&Alds[row * 64 + sw * 8];
      }
#pragma unroll
      for (int nn = 0; nn < 4; ++nn) {
        int row = wc * 64 + nn * 16 + fr;
        int sw = (ks * 4 + kg) ^ (row & 7);
        bfv[nn] = *(const bf16x8*)&Blds[row * 64 + sw * 8];
      }
#pragma unroll
      for (int mt = 0; mt < 4; ++mt)
#pragma unroll
        for (int nn = 0; nn < 4; ++nn)
          acc[mt][nn] = __builtin_amdgcn_mfma_f32_16x16x32_bf16(af[mt], bfv[nn], acc[mt][nn], 0, 0, 0);
    }
  }

  float* Cb = C + ((size_t)b << 16);
#pragma unroll
  for (int mt = 0; mt < 4; ++mt)
#pragma unroll
    for (int nn = 0; nn < 4; ++nn)
#pragma unroll
      for (int r = 0; r < 4; ++r) {
        int n = n0 + wr * 64 + mt * 16 + kg * 4 + r;
        int j = j0 + wc * 64 + nn * 16 + fr;
        atomicAdd(&Cb[n * 256 + j], acc[mt][nn][r] * 0.02f);
      }
}

// ------------------------------------------------------------------ launch --
extern "C" void kernel_launch(void* const* d_in, const int* in_sizes, int n_in,
                              void* d_out, int out_size, void* d_ws, size_t ws_size,
                              hipStream_t stream)
{
  const float* rbf0 = (const float*)d_in[0];
  const float* rbfd = (const float*)d_in[1];
  const float* Q0w  = (const float*)d_in[2];
  const float* Q0b  = (const float*)d_in[3];
  const float* Qw   = (const float*)d_in[4];
  const float* Qb   = (const float*)d_in[5];
  const float* R0w  = (const float*)d_in[6];
  const float* R0b  = (const float*)d_in[7];
  const float* Rw   = (const float*)d_in[8];
  const float* Rb   = (const float*)d_in[9];
  float* out = (float*)d_out;

  u16* Abuf = (u16*)d_ws;
  u16* Bbuf = Abuf + (size_t)33554432;

  hipMemsetAsync(d_out, 0, (size_t)out_size * sizeof(float), stream);
  hipLaunchKernelGGL(k_phase1, dim3(2048), dim3(256), 0, stream,
                     rbf0, rbfd, Q0w, Q0b, Qw, Qb, R0w, R0b, Rw, Rb, Abuf, Bbuf);
  hipLaunchKernelGGL(k_phase2, dim3(512), dim3(256), 0, stream, Abuf, Bbuf, out);
}

// Round 6
// 141.763 us; speedup vs baseline: 1.0022x; 1.0022x over previous
//
#include <hip/hip_runtime.h>
#include <hip/hip_bf16.h>

// CorrelatorK3: B=8, N=256, D=64, F=64
// Stage 1 (global_load_lds NT staging, 3-set LDS, depth-2 counted-vmcnt pipeline):
//   A[p,kk]  = (rbf0[p]·Q0w+Q0b) * (rbfd[p]·Qw+Qb)   (bf16, f-permuted kk)
//   Bm[p,kk] = (rbf0[p]·R0w+R0b) * (rbfd[p]·Rw+Rb)   (bf16, f-permuted kk)
//   kk = kg*16 + ft*4 + r  <->  f = ft*16 + kg*4 + r (same perm both bufs)
// Stage 2: C[b,n,j] = 0.02 * sum_{i,kk} A[b,n,i,kk] * Bm[b,i,j,kk]
//
// R6 change (single variable): input staging loads are NON-TEMPORAL (aux=2,
// gfx940+ CPol NT bit). Inputs are read exactly once; NT keeps them from
// allocating in Infinity Cache, so the LLC retains the (normally-written)
// 128 MiB workspace -> phase-1 stops writing back to DRAM, phase-2 reads
// workspace from LLC (measured 13 TB/s in R5).

typedef __bf16 bf16x8 __attribute__((ext_vector_type(8)));
typedef float  f32x4  __attribute__((ext_vector_type(4)));
typedef int    i32x4  __attribute__((ext_vector_type(4)));
typedef unsigned short u16;
typedef u16    u16x8  __attribute__((ext_vector_type(8)));

static __device__ __forceinline__ __bf16 f2bf(float x) {
  union { __hip_bfloat16 h; __bf16 b; } u;
  u.h = __float2bfloat16(x);
  return u.b;
}
static __device__ __forceinline__ u16 f2bfu(float x) {
  union { __hip_bfloat16 h; u16 s; } u;
  u.h = __float2bfloat16(x);
  return u.s;
}
static __device__ __forceinline__ float bfu2f(u16 s) {
  union { unsigned int u; float f; } v;
  v.u = ((unsigned int)s) << 16;
  return v.f;
}
static __device__ __forceinline__ void gload16_nt(const float* gsrc, float* ldst) {
  // aux=2: CPol NT (non-temporal) on gfx940+/gfx950
  __builtin_amdgcn_global_load_lds(
      (const __attribute__((address_space(1))) void*)gsrc,
      (__attribute__((address_space(3))) void*)ldst, 16, 0, 2);
}

// ---------------------------------------------------------------- stage 1 ---
// Grid MUST be 2048 x 256thr (4 waves). Block-tile = 32 positions (16 KB).
// 3 LDS sets (48 KB), depth-2 prefetch via global_load_lds width=16.
// Global source is PRE-SWIZZLED (involution c^=(c>>4)&15 within 16-chunk
// windows -> coalescing preserved); LDS dest linear (gl_lds requirement);
// LDS reads use the same swizzle. Per-wave per-iter vmem ops: 4 gl_lds + 2
// stores -> counted vmcnt N[it] = {8,10,12,12,12,12,8,4} (never 0 in loop).
__global__ __launch_bounds__(256, 3) void k_phase1(
    const float* __restrict__ rbf0, const float* __restrict__ rbfd,
    const float* __restrict__ Q0w, const float* __restrict__ Q0b,
    const float* __restrict__ Qw,  const float* __restrict__ Qb,
    const float* __restrict__ R0w, const float* __restrict__ R0b,
    const float* __restrict__ Rw,  const float* __restrict__ Rb,
    u16* __restrict__ Aout, u16* __restrict__ Bout)
{
  __shared__ __align__(16) float lds[3][2][2048];

  const int tid  = threadIdx.x;
  const int lane = tid & 63;
  const int wave = tid >> 6;
  const int fr   = lane & 15;
  const int kg   = lane >> 4;
  const int role = wave >> 1;   // 0: Q-path (A), 1: R-path (Bm)
  const int s    = wave & 1;    // 16-pos sub-tile

  const float* W0 = role ? R0w : Q0w;
  const float* W1 = role ? Rw  : Qw;
  const float* B0 = role ? R0b : Q0b;
  const float* B1 = role ? Rb  : Qb;
  u16* __restrict__ Out = role ? Bout : Aout;

  // Weight A-frags: lane holds W[ft*16+fr][kt*32+kg*8+j]
  bf16x8 wf0[2][4], wf1[2][4];
#pragma unroll
  for (int kt = 0; kt < 2; ++kt)
#pragma unroll
    for (int ft = 0; ft < 4; ++ft) {
      const float* p0 = W0 + (ft * 16 + fr) * 64 + kt * 32 + kg * 8;
      const float* p1 = W1 + (ft * 16 + fr) * 64 + kt * 32 + kg * 8;
      f32x4 a = *(const f32x4*)p0, b = *(const f32x4*)(p0 + 4);
      f32x4 c = *(const f32x4*)p1, d = *(const f32x4*)(p1 + 4);
      bf16x8 w0v, w1v;
#pragma unroll
      for (int j = 0; j < 4; ++j) {
        w0v[j] = f2bf(a[j]); w0v[j + 4] = f2bf(b[j]);
        w1v[j] = f2bf(c[j]); w1v[j + 4] = f2bf(d[j]);
      }
      wf0[kt][ft] = w0v; wf1[kt][ft] = w1v;
    }

  // Bias, permuted idx = ft*4+r (value b[ft*16+kg*4+r]), packed bf16
  u16x8 pb0[2], pb1[2];
#pragma unroll
  for (int ft = 0; ft < 4; ++ft)
#pragma unroll
    for (int r = 0; r < 4; ++r) {
      int idx = ft * 4 + r;
      pb0[idx >> 3][idx & 7] = f2bfu(B0[ft * 16 + kg * 4 + r]);
      pb1[idx >> 3][idx & 7] = f2bfu(B1[ft * 16 + kg * 4 + r]);
    }

  // Pre-swizzled global chunk indices (involution; float offsets = chunk*4).
  const int g0 = tid, g1 = 256 + tid;
  const int c0 = ((g0 >> 4) << 4) | ((g0 & 15) ^ ((g0 >> 4) & 15));
  const int c1 = ((g1 >> 4) << 4) | ((g1 & 15) ^ ((g1 >> 4) & 15));
  const int f0 = c0 * 4, f1 = c1 * 4;                 // float offsets
  const int d0 = wave * 256, d1 = (wave + 4) * 256;   // LDS float offsets (linear)

  const int bt0 = blockIdx.x;   // gridDim.x == 2048, 8 tiles/block

#define S1_ISSUE(IT, SET)                                              \
  {                                                                    \
    const float* b0_ = rbf0 + (size_t)(bt0 + (IT) * 2048) * 2048;      \
    const float* b1_ = rbfd + (size_t)(bt0 + (IT) * 2048) * 2048;      \
    gload16_nt(b0_ + f0, &lds[SET][0][d0]);                            \
    gload16_nt(b0_ + f1, &lds[SET][0][d1]);                            \
    gload16_nt(b1_ + f0, &lds[SET][1][d0]);                            \
    gload16_nt(b1_ + f1, &lds[SET][1][d1]);                            \
  }

#define S1_COMPUTE(IT, SET)                                            \
  {                                                                    \
    const int row = s * 16 + fr; /* row&15 == fr */                    \
    f32x4 ra[4], rb[4];                                                \
    _Pragma("unroll")                                                  \
    for (int kt = 0; kt < 2; ++kt)                                     \
      _Pragma("unroll")                                                \
      for (int h = 0; h < 2; ++h) {                                    \
        int c = kt * 8 + kg * 2 + h;                                   \
        int chunk = (row << 4) | (c ^ fr);                             \
        ra[kt * 2 + h] = *(const f32x4*)&lds[SET][0][chunk * 4];       \
        rb[kt * 2 + h] = *(const f32x4*)&lds[SET][1][chunk * 4];       \
      }                                                                \
    bf16x8 x0f[2], xdf[2];                                             \
    _Pragma("unroll")                                                  \
    for (int kt = 0; kt < 2; ++kt)                                     \
      _Pragma("unroll")                                                \
      for (int j = 0; j < 4; ++j) {                                    \
        x0f[kt][j]     = f2bf(ra[kt * 2][j]);                          \
        x0f[kt][j + 4] = f2bf(ra[kt * 2 + 1][j]);                      \
        xdf[kt][j]     = f2bf(rb[kt * 2][j]);                          \
        xdf[kt][j + 4] = f2bf(rb[kt * 2 + 1][j]);                      \
      }                                                                \
    f32x4 acc0[4], acc1[4];                                            \
    _Pragma("unroll")                                                  \
    for (int ft = 0; ft < 4; ++ft)                                     \
      _Pragma("unroll")                                                \
      for (int r = 0; r < 4; ++r) {                                    \
        int idx = ft * 4 + r;                                          \
        acc0[ft][r] = bfu2f(pb0[idx >> 3][idx & 7]);                   \
        acc1[ft][r] = bfu2f(pb1[idx >> 3][idx & 7]);                   \
      }                                                                \
    _Pragma("unroll")                                                  \
    for (int kt = 0; kt < 2; ++kt)                                     \
      _Pragma("unroll")                                                \
      for (int ft = 0; ft < 4; ++ft) {                                 \
        acc0[ft] = __builtin_amdgcn_mfma_f32_16x16x32_bf16(            \
            wf0[kt][ft], x0f[kt], acc0[ft], 0, 0, 0);                  \
        acc1[ft] = __builtin_amdgcn_mfma_f32_16x16x32_bf16(            \
            wf1[kt][ft], xdf[kt], acc1[ft], 0, 0, 0);                  \
      }                                                                \
    u16x8 o0, o1;                                                      \
    _Pragma("unroll")                                                  \
    for (int ft = 0; ft < 4; ++ft)                                     \
      _Pragma("unroll")                                                \
      for (int r = 0; r < 4; ++r) {                                    \
        int idx = ft * 4 + r;                                          \
        float v = acc0[ft][r] * acc1[ft][r];                           \
        if (idx < 8) o0[idx & 7] = f2bfu(v); else o1[idx & 7] = f2bfu(v); \
      }                                                                \
    u16* dst = Out + ((size_t)((bt0 + (IT) * 2048) * 32 + s * 16 + fr)) * 64 + kg * 16; \
    *(u16x8*)dst       = o0;                                           \
    *(u16x8*)(dst + 8) = o1;                                           \
  }

#define S1_ITER(IT, NWAIT, DO_ISSUE)                                   \
  {                                                                    \
    if (DO_ISSUE) S1_ISSUE((IT) + 2, ((IT) + 2) % 3);                  \
    asm volatile("s_waitcnt vmcnt(" #NWAIT ")" ::: "memory");          \
    __builtin_amdgcn_s_barrier();                                      \
    __builtin_amdgcn_sched_barrier(0);                                 \
    S1_COMPUTE(IT, (IT) % 3);                                          \
    asm volatile("s_waitcnt lgkmcnt(0)" ::: "memory");                 \
    __builtin_amdgcn_s_barrier();                                      \
    __builtin_amdgcn_sched_barrier(0);                                 \
  }

  // prologue: tiles 0,1 -> sets 0,1
  S1_ISSUE(0, 0);
  S1_ISSUE(1, 1);

  S1_ITER(0,  8, 1);
  S1_ITER(1, 10, 1);
  S1_ITER(2, 12, 1);
  S1_ITER(3, 12, 1);
  S1_ITER(4, 12, 1);
  S1_ITER(5, 12, 1);
  S1_ITER(6,  8, 0);
  S1_ITER(7,  4, 0);

#undef S1_ITER
#undef S1_COMPUTE
#undef S1_ISSUE
}

// ---------------------------------------------------------------- stage 2 ---
// Grid: 512 blocks = 8 b * 2 nt * 2 jt * 16 kc. Block = 4 waves (2x2), tile 128x128.
__global__ __launch_bounds__(256, 2) void k_phase2(
    const u16* __restrict__ A, const u16* __restrict__ Bm,
    float* __restrict__ C)
{
  __shared__ __align__(16) u16 Alds[128 * 64];
  __shared__ __align__(16) u16 Blds[128 * 64];

  const int tid  = threadIdx.x;
  const int lane = tid & 63;
  const int wave = tid >> 6;
  const int fr   = lane & 15;
  const int kg   = lane >> 4;

  const int bid = blockIdx.x;
  const int kc = bid & 15;
  const int jt = (bid >> 4) & 1;
  const int nt = (bid >> 5) & 1;
  const int b  = bid >> 6;          // [0,8)
  const int n0 = nt * 128, j0 = jt * 128;
  const int wr = wave >> 1, wc = wave & 1;

  const u16* Ab = A  + (size_t)b * 4194304;
  const u16* Bb = Bm + (size_t)b * 4194304;

  f32x4 acc[4][4];
#pragma unroll
  for (int mt = 0; mt < 4; ++mt)
#pragma unroll
    for (int nn = 0; nn < 4; ++nn) {
      acc[mt][nn][0] = 0.f; acc[mt][nn][1] = 0.f; acc[mt][nn][2] = 0.f; acc[mt][nn][3] = 0.f;
    }

  for (int ii = 0; ii < 16; ++ii) {
    const int i = kc * 16 + ii;

    i32x4 va[4], vb[4];
#pragma unroll
    for (int rep = 0; rep < 4; ++rep) {
      int c = tid + rep * 256;
      int row = c >> 3, ch = c & 7;
      va[rep] = *(const i32x4*)(Ab + (size_t)(n0 + row) * 16384 + (size_t)i * 64 + ch * 8);
      vb[rep] = *(const i32x4*)(Bb + (size_t)i * 16384 + (size_t)(j0 + row) * 64 + ch * 8);
    }
    __syncthreads();
#pragma unroll
    for (int rep = 0; rep < 4; ++rep) {
      int c = tid + rep * 256;
      int row = c >> 3, ch = c & 7;
      int sw = ch ^ (row & 7);
      *(i32x4*)&Alds[row * 64 + sw * 8] = va[rep];
      *(i32x4*)&Blds[row * 64 + sw * 8] = vb[rep];
    }
    __syncthreads();

#pragma unroll
    for (int ks = 0; ks < 2; ++ks) {
      bf16x8 af[4], bfv[4];
#pragma unroll
      for (int mt = 0; mt < 4; ++mt) {
        int row = wr * 64 + mt * 16 + fr;
        int sw = (ks * 4 + kg) ^ (row & 7);
        af[mt] = *(const bf16x8*)&Alds[row * 64 + sw * 8];
      }
#pragma unroll
      for (int nn = 0; nn < 4; ++nn) {
        int row = wc * 64 + nn * 16 + fr;
        int sw = (ks * 4 + kg) ^ (row & 7);
        bfv[nn] = *(const bf16x8*)&Blds[row * 64 + sw * 8];
      }
#pragma unroll
      for (int mt = 0; mt < 4; ++mt)
#pragma unroll
        for (int nn = 0; nn < 4; ++nn)
          acc[mt][nn] = __builtin_amdgcn_mfma_f32_16x16x32_bf16(af[mt], bfv[nn], acc[mt][nn], 0, 0, 0);
    }
  }

  float* Cb = C + ((size_t)b << 16);
#pragma unroll
  for (int mt = 0; mt < 4; ++mt)
#pragma unroll
    for (int nn = 0; nn < 4; ++nn)
#pragma unroll
      for (int r = 0; r < 4; ++r) {
        int n = n0 + wr * 64 + mt * 16 + kg * 4 + r;
        int j = j0 + wc * 64 + nn * 16 + fr;
        atomicAdd(&Cb[n * 256 + j], acc[mt][nn][r] * 0.02f);
      }
}

// ------------------------------------------------------------------ launch --
extern "C" void kernel_launch(void* const* d_in, const int* in_sizes, int n_in,
                              void* d_out, int out_size, void* d_ws, size_t ws_size,
                              hipStream_t stream)
{
  const float* rbf0 = (const float*)d_in[0];
  const float* rbfd = (const float*)d_in[1];
  const float* Q0w  = (const float*)d_in[2];
  const float* Q0b  = (const float*)d_in[3];
  const float* Qw   = (const float*)d_in[4];
  const float* Qb   = (const float*)d_in[5];
  const float* R0w  = (const float*)d_in[6];
  const float* R0b  = (const float*)d_in[7];
  const float* Rw   = (const float*)d_in[8];
  const float* Rb   = (const float*)d_in[9];
  float* out = (float*)d_out;

  u16* Abuf = (u16*)d_ws;
  u16* Bbuf = Abuf + (size_t)33554432;

  hipMemsetAsync(d_out, 0, (size_t)out_size * sizeof(float), stream);
  hipLaunchKernelGGL(k_phase1, dim3(2048), dim3(256), 0, stream,
                     rbf0, rbfd, Q0w, Q0b, Qw, Qb, R0w, R0b, Rw, Rb, Abuf, Bbuf);
  hipLaunchKernelGGL(k_phase2, dim3(512), dim3(256), 0, stream, Abuf, Bbuf, out);
}